// Round 3
// baseline (1190.917 us; speedup 1.0000x reference)
//
#include <hip/hip_runtime.h>
#include <hip/hip_cooperative_groups.h>
#include <math.h>

namespace cg = cooperative_groups;

// Problem constants
constexpr int NND = 8192;           // N nodes
constexpr int FD  = 512;            // features
constexpr int HD  = 128;            // hidden
constexpr int ED  = 262144;         // edges
constexpr long long NF_ = (long long)NND * FD;      // 4,194,304
constexpr long long NN_ = (long long)NND * NND;     // 67,108,864
constexpr long long NF4 = NF_ / 4;                  // 1,048,576 quads
constexpr long long NN4 = NN_ / 4;                  // 16,777,216 quads

constexpr int NBLK  = 1024;
constexpr int NTHR  = 256;
constexpr int GEMMB = 512;                          // blocks 0..511: GEMM (16 rows each)
constexpr int FILLT = (NBLK - GEMMB) * NTHR;        // 131072 fill threads (mult of 128)

// ---- order-preserving float <-> uint for atomic min/max ----
__device__ __forceinline__ unsigned fkey(float f) {
    unsigned b = __float_as_uint(f);
    return (b & 0x80000000u) ? ~b : (b | 0x80000000u);
}
__device__ __forceinline__ float fdec(unsigned k) {
    return (k & 0x80000000u) ? __uint_as_float(k ^ 0x80000000u)
                             : __uint_as_float(~k);
}

// ctrl: [0]=min key, [1]=max key, [2]=cnt_unique, [3]=cnt_nonzero

struct KP {
    const float* x; const int* row; const int* col;
    const float* W; const float* Wedge; const float* bedge;
    const float* noise; const float* masku;
    float* out; float* xw; float* elog; float* u; float* v;
    int* row_start; int* cursor; int* scol; int* counts;
    unsigned char* hard; unsigned* ctrl; float* rate;
};

__global__ __launch_bounds__(256, 4) void kcoop(KP p) {
    cg::grid_group grid = cg::this_grid();
    const int tid = threadIdx.x;
    const int bid = blockIdx.x;
    const int gid = bid * NTHR + tid;           // 0 .. 262143 (== ED)
    int* adjI = (int*)(p.out + NF_);

    __shared__ int   ssc[256];
    __shared__ float su[2][2], sv[2][2];

    // ---- P0: init counts + ctrl ----
    if (gid < NND) p.counts[gid] = 0;
    if (gid == 0) { p.ctrl[0] = 0xFFFFFFFFu; p.ctrl[1] = 0u; p.ctrl[2] = 0u; p.ctrl[3] = 0u; }
    grid.sync();

    // ---- P1: GEMM (blocks 0..511) || feature+zero-fill+histogram (blocks 512..1023) ----
    if (bid < GEMMB) {
        // fp32 GEMM xw = x @ W_enc: block = 16 rows x 128 cols; thread = 2 rows x 4 cols
        int tx = tid & 31, ty = tid >> 5;
        int m0 = bid * 16 + ty * 2;
        const float* xr0 = p.x + (long long)m0 * FD;
        const float* xr1 = xr0 + FD;
        float a0[4] = {0.f, 0.f, 0.f, 0.f};
        float a1[4] = {0.f, 0.f, 0.f, 0.f};
#pragma unroll 4
        for (int k = 0; k < FD; ++k) {
            float s0 = xr0[k], s1 = xr1[k];
            float4 b = *(const float4*)(p.W + k * HD + tx * 4);
            a0[0] = fmaf(s0, b.x, a0[0]);
            a0[1] = fmaf(s0, b.y, a0[1]);
            a0[2] = fmaf(s0, b.z, a0[2]);
            a0[3] = fmaf(s0, b.w, a0[3]);
            a1[0] = fmaf(s1, b.x, a1[0]);
            a1[1] = fmaf(s1, b.y, a1[1]);
            a1[2] = fmaf(s1, b.z, a1[2]);
            a1[3] = fmaf(s1, b.w, a1[3]);
        }
        *(float4*)(p.xw + (long long)m0 * HD + tx * 4) =
            make_float4(a0[0], a0[1], a0[2], a0[3]);
        *(float4*)(p.xw + (long long)(m0 + 1) * HD + tx * 4) =
            make_float4(a1[0], a1[1], a1[2], a1[3]);
    } else {
        int fid = (bid - GEMMB) * NTHR + tid;   // 0 .. 131071
        // edge histogram (counts zeroed in P0)
        atomicAdd(&p.counts[p.row[fid]], 1);
        atomicAdd(&p.counts[p.row[fid + FILLT]], 1);
        // feature = masked x (FILLT is a multiple of 128 -> column quad constant)
        int c4 = (fid & 127) * 4;
        float kx = (p.masku[c4 + 0] < 0.2f) ? 0.f : 1.f;
        float ky = (p.masku[c4 + 1] < 0.2f) ? 0.f : 1.f;
        float kz = (p.masku[c4 + 2] < 0.2f) ? 0.f : 1.f;
        float kw = (p.masku[c4 + 3] < 0.2f) ? 0.f : 1.f;
        const float4* xq = (const float4*)p.x;
        float4* oq = (float4*)p.out;
        for (long long q = fid; q < NF4; q += FILLT) {
            float4 xv = xq[q];
            float4 o;
            o.x = xv.x * kx; o.y = xv.y * ky; o.z = xv.z * kz; o.w = xv.w * kw;
            oq[q] = o;
        }
        // zero the dense adj region
        float4 z = make_float4(0.f, 0.f, 0.f, 0.f);
        for (long long q = NF4 + fid; q < NF4 + NN4; q += FILLT)
            oq[q] = z;
    }
    grid.sync();

    // ---- P2: exclusive scan of counts -> row_start[8193], cursor (block 0) ----
    if (bid == 0) {
        int c[32];
        int sum = 0;
        const int4* cp = (const int4*)p.counts;
#pragma unroll
        for (int j = 0; j < 8; ++j) {
            int4 vv = cp[tid * 8 + j];
            c[j * 4 + 0] = vv.x; c[j * 4 + 1] = vv.y;
            c[j * 4 + 2] = vv.z; c[j * 4 + 3] = vv.w;
            sum += vv.x + vv.y + vv.z + vv.w;
        }
        ssc[tid] = sum;
        __syncthreads();
        for (int d = 1; d < 256; d <<= 1) {
            int add = (tid >= d) ? ssc[tid - d] : 0;
            __syncthreads();
            ssc[tid] += add;
            __syncthreads();
        }
        int run = (tid == 0) ? 0 : ssc[tid - 1];
#pragma unroll
        for (int j = 0; j < 32; ++j) {
            p.row_start[tid * 32 + j] = run;
            p.cursor[tid * 32 + j] = run;
            run += c[j];
        }
        if (tid == 255) p.row_start[8192] = run;
    }
    grid.sync();

    // ---- P3: bucket edges by row ----
    {
        int r = p.row[gid];
        int pos = atomicAdd(&p.cursor[r], 1);
        p.scol[pos] = p.col[gid];
    }
    grid.sync();

    // ---- P4: agg = segment_sum(xw[col]); relu; u = agg@W1, v = agg@W2 ----
    {
        int t = tid & 127, half = tid >> 7;
        int w = (tid >> 6) & 1;
        for (int rep = 0; rep < 4; ++rep) {
            int i = bid * 8 + rep * 2 + half;
            int s0 = p.row_start[i], s1 = p.row_start[i + 1];
            float acc = 0.f;
            int j = s0;
            for (; j + 4 <= s1; j += 4) {
                int c0 = p.scol[j], c1 = p.scol[j + 1];
                int c2 = p.scol[j + 2], c3 = p.scol[j + 3];
                float v0 = p.xw[(long long)c0 * HD + t];
                float v1 = p.xw[(long long)c1 * HD + t];
                float v2 = p.xw[(long long)c2 * HD + t];
                float v3 = p.xw[(long long)c3 * HD + t];
                acc += v0; acc += v1; acc += v2; acc += v3;
            }
            for (; j < s1; ++j) acc += p.xw[(long long)p.scol[j] * HD + t];
            acc = fmaxf(acc, 0.f);

            float up = acc * p.Wedge[t];
            float vp = acc * p.Wedge[HD + t];
#pragma unroll
            for (int off = 32; off > 0; off >>= 1) {
                up += __shfl_down(up, off);
                vp += __shfl_down(vp, off);
            }
            if ((tid & 63) == 0) { su[half][w] = up; sv[half][w] = vp; }
            __syncthreads();
            if (t == 0) {
                p.u[i] = su[half][0] + su[half][1];
                p.v[i] = sv[half][0] + sv[half][1];
            }
            __syncthreads();
        }
    }
    grid.sync();

    // ---- P5: edge logits + global min/max ----
    {
        float el = p.u[p.row[gid]] + p.v[p.col[gid]] + p.bedge[0];
        p.elog[gid] = el;
        float mn = el, mx = el;
#pragma unroll
        for (int off = 32; off > 0; off >>= 1) {
            mn = fminf(mn, __shfl_xor(mn, off));
            mx = fmaxf(mx, __shfl_xor(mx, off));
        }
        if ((tid & 63) == 0) {
            atomicMin(&p.ctrl[0], fkey(mn));
            atomicMax(&p.ctrl[1], fkey(mx));
        }
    }
    grid.sync();

    // ---- P6: hard bit + winner election (last-edge-wins via max(e+1)) ----
    {
        float lo = fdec(p.ctrl[0]);
        float hi = fdec(p.ctrl[1]);
        float kk = 0.3f / (hi - lo);                // ub=0.3, lb=0
        float pr = kk * (p.elog[gid] - lo);
        float lp = logf(pr + 1e-10f) - log1pf(1e-10f - pr);
        long long cell = (long long)p.row[gid] * NND + p.col[gid];
        float nz = p.noise[cell];
        float lg = logf(nz) - log1pf(-nz);
        int h = ((lp + lg) > 0.f) ? 1 : 0;          // round(sigmoid(z/T)) == (z>0)
        p.hard[gid] = (unsigned char)h;
        atomicMax(&adjI[cell], gid + 1);
    }
    grid.sync();

    // ---- P7: winner writes adj value; count unique & nonzero cells ----
    {
        long long cell = (long long)p.row[gid] * NND + p.col[gid];
        int w = adjI[cell];
        bool win = (w == gid + 1);
        bool nzv = win && (p.hard[gid] == 0);
        if (win) ((float*)adjI)[cell] = nzv ? 1.0f : 0.0f;
        unsigned long long mw = __ballot(win);
        unsigned long long mz = __ballot(nzv);
        if ((tid & 63) == 0) {
            atomicAdd(&p.ctrl[2], (unsigned)__popcll(mw));
            atomicAdd(&p.ctrl[3], (unsigned)__popcll(mz));
        }
    }
    grid.sync();

    // ---- P8: adj_aug_rate ----
    if (gid == 0) p.rate[0] = (float)p.ctrl[3] / (float)p.ctrl[2];
}

extern "C" void kernel_launch(void* const* d_in, const int* in_sizes, int n_in,
                              void* d_out, int out_size, void* d_ws, size_t ws_size,
                              hipStream_t stream) {
    char* ws = (char*)d_ws;

    KP p;
    p.x     = (const float*)d_in[0];
    p.row   = (const int*)d_in[1];
    p.col   = (const int*)d_in[2];
    p.W     = (const float*)d_in[3];
    p.Wedge = (const float*)d_in[4];
    p.bedge = (const float*)d_in[5];
    p.noise = (const float*)d_in[6];
    p.masku = (const float*)d_in[7];
    p.out   = (float*)d_out;

    p.xw        = (float*)(ws);                      // 4 MB
    p.elog      = (float*)(ws + 4194304);            // 1 MB
    p.u         = (float*)(ws + 5242880);            // 32 KB
    p.v         = (float*)(ws + 5275648);            // 32 KB
    p.row_start = (int*)  (ws + 5308416);            // 32772 B (res 36864)
    p.cursor    = (int*)  (ws + 5345280);            // 32 KB
    p.scol      = (int*)  (ws + 5378048);            // 1 MB
    p.counts    = (int*)  (ws + 6426624);            // 32 KB
    p.hard      = (unsigned char*)(ws + 6459392);    // 256 KB
    p.ctrl      = (unsigned*)(ws + 6721536);         // 64 B
    p.rate      = (float*)d_out + NF_ + NN_;

    void* args[] = { &p };
    hipLaunchCooperativeKernel((void*)kcoop, dim3(NBLK), dim3(NTHR), args, 0, stream);
}

// Round 4
// 266.478 us; speedup vs baseline: 4.4691x; 4.4691x over previous
//
#include <hip/hip_runtime.h>
#include <math.h>

// Problem constants
constexpr int NND = 8192;           // N nodes
constexpr int FD  = 512;            // features
constexpr int HD  = 128;            // hidden
constexpr int ED  = 262144;         // edges
constexpr long long NF_ = (long long)NND * FD;      // 4,194,304
constexpr long long NN_ = (long long)NND * NND;     // 67,108,864
constexpr long long NF4 = NF_ / 4;                  // 1,048,576 quads
constexpr long long NN4 = NN_ / 4;                  // 16,777,216 quads

// zero-fill quad partition of the dense adj region (units: float4 quads)
constexpr long long Z_K1 = 0;              // k1: 6 * 1048576
constexpr long long Z_KD = 6291456;        // kD: 4 * 262144
constexpr long long Z_KE = 7340032;        // kE: 8 * 1048576
constexpr long long Z_KF = 15728640;       // kF: 4 * 262144  (ends at 16777216)

constexpr int GEMMB = 512;                 // k1 blocks 0..511: GEMM (16 rows each)
constexpr int FILLB = 4096;                // k1 fill blocks
constexpr int FILLT = FILLB * 256;         // 1,048,576 fill threads

// ctrl words: [4]=ticketF, [5]=ticketH, [8..9]=float lo/hi (written by kF)

// K0: zero counts + ctrl.
__global__ void k0_init(int* __restrict__ counts, unsigned* __restrict__ ctrl) {
    int t = blockIdx.x * 256 + threadIdx.x;
    if (t < NND) counts[t] = 0;
    if (t < 16) ctrl[t] = 0u;
}

// K1: blocks [0,512) = fp32 GEMM xw = x@W_enc + edge histogram;
//     blocks [512,4608) = feature mask + 6/16 of adj zero-fill.
__global__ __launch_bounds__(256) void k1_mega(const float* __restrict__ x,
                                               const float* __restrict__ W,
                                               const float* __restrict__ mask_u,
                                               const int* __restrict__ row,
                                               float* __restrict__ out,
                                               float* __restrict__ xw,
                                               int* __restrict__ counts) {
    int tid = threadIdx.x;
    if (blockIdx.x < GEMMB) {
        int bid = blockIdx.x;
        // edge histogram (counts pre-zeroed by k0)
        int g2 = bid * 256 + tid;
        atomicAdd(&counts[row[g2]], 1);
        atomicAdd(&counts[row[g2 + 131072]], 1);

        // GEMM: block = 16 rows x 128 cols; thread = 2 rows x 4 cols.
        int tx = tid & 31, ty = tid >> 5;
        int m0 = bid * 16 + ty * 2;
        const float* xr0 = x + (long long)m0 * FD;
        const float* xr1 = xr0 + FD;
        float a0[4] = {0.f, 0.f, 0.f, 0.f};
        float a1[4] = {0.f, 0.f, 0.f, 0.f};
#pragma unroll 4
        for (int k = 0; k < FD; ++k) {
            float s0 = xr0[k], s1 = xr1[k];
            float4 b = *(const float4*)(W + k * HD + tx * 4);
            a0[0] = fmaf(s0, b.x, a0[0]);
            a0[1] = fmaf(s0, b.y, a0[1]);
            a0[2] = fmaf(s0, b.z, a0[2]);
            a0[3] = fmaf(s0, b.w, a0[3]);
            a1[0] = fmaf(s1, b.x, a1[0]);
            a1[1] = fmaf(s1, b.y, a1[1]);
            a1[2] = fmaf(s1, b.z, a1[2]);
            a1[3] = fmaf(s1, b.w, a1[3]);
        }
        *(float4*)(xw + (long long)m0 * HD + tx * 4) =
            make_float4(a0[0], a0[1], a0[2], a0[3]);
        *(float4*)(xw + (long long)(m0 + 1) * HD + tx * 4) =
            make_float4(a1[0], a1[1], a1[2], a1[3]);
    } else {
        int fid = (blockIdx.x - GEMMB) * 256 + tid;   // 0 .. 1048575
        // feature = masked x (fid covers NF4 exactly once; column quad = fid&127)
        int c4 = (fid & 127) * 4;
        float kx = (mask_u[c4 + 0] < 0.2f) ? 0.f : 1.f;
        float ky = (mask_u[c4 + 1] < 0.2f) ? 0.f : 1.f;
        float kz = (mask_u[c4 + 2] < 0.2f) ? 0.f : 1.f;
        float kw = (mask_u[c4 + 3] < 0.2f) ? 0.f : 1.f;
        float4 xv = ((const float4*)x)[fid];
        float4 o;
        o.x = xv.x * kx; o.y = xv.y * ky; o.z = xv.z * kz; o.w = xv.w * kw;
        ((float4*)out)[fid] = o;
        // 6/16 of the dense adj zero-fill
        float4* zq = (float4*)(out + NF_);
        float4 z = make_float4(0.f, 0.f, 0.f, 0.f);
#pragma unroll
        for (int j = 0; j < 6; ++j)
            zq[Z_K1 + fid + (long long)j * FILLT] = z;
    }
}

// K_C: exclusive scan of per-row counts -> row_start[N+1], cursor[N]. 1 block/256.
__global__ __launch_bounds__(256) void kC_scan(const int* __restrict__ counts,
                                               int* __restrict__ row_start,
                                               int* __restrict__ cursor) {
    __shared__ int ssc[256];
    int t = threadIdx.x;
    int c[32];
    int sum = 0;
    const int4* cp = (const int4*)counts;
#pragma unroll
    for (int j = 0; j < 8; ++j) {
        int4 vv = cp[t * 8 + j];
        c[j * 4 + 0] = vv.x; c[j * 4 + 1] = vv.y;
        c[j * 4 + 2] = vv.z; c[j * 4 + 3] = vv.w;
        sum += vv.x + vv.y + vv.z + vv.w;
    }
    ssc[t] = sum;
    __syncthreads();
    for (int d = 1; d < 256; d <<= 1) {
        int add = (t >= d) ? ssc[t - d] : 0;
        __syncthreads();
        ssc[t] += add;
        __syncthreads();
    }
    int run = (t == 0) ? 0 : ssc[t - 1];
#pragma unroll
    for (int j = 0; j < 32; ++j) {
        row_start[t * 32 + j] = run;
        cursor[t * 32 + j] = run;
        run += c[j];
    }
    if (t == 255) row_start[8192] = run;
}

// K_D: bucket edges by row; +1/16 fill.
__global__ void kD_scatter(const int* __restrict__ row, const int* __restrict__ col,
                           int* __restrict__ cursor, int* __restrict__ scol,
                           float4* __restrict__ zq) {
    int e = blockIdx.x * 256 + threadIdx.x;
    int r = row[e];
    int pos = atomicAdd(&cursor[r], 1);
    scol[pos] = col[e];
    float4 z = make_float4(0.f, 0.f, 0.f, 0.f);
#pragma unroll
    for (int j = 0; j < 4; ++j)
        zq[Z_KD + e + (long long)j * ED] = z;
}

// K_E: agg[i] = sum_{edges of i} xw[col]; relu; u=agg@W1, v=agg@W2; +8/16 fill.
__global__ __launch_bounds__(128) void kE_spmm_uv(const float* __restrict__ xw,
                                                  const int* __restrict__ row_start,
                                                  const int* __restrict__ scol,
                                                  const float* __restrict__ Wedge,
                                                  float* __restrict__ u,
                                                  float* __restrict__ v,
                                                  float4* __restrict__ zq) {
    int i = blockIdx.x, t = threadIdx.x;
    int s0 = row_start[i], s1 = row_start[i + 1];
    float acc = 0.f;
    int j = s0;
    for (; j + 4 <= s1; j += 4) {
        int c0 = scol[j], c1 = scol[j + 1], c2 = scol[j + 2], c3 = scol[j + 3];
        float v0 = xw[(long long)c0 * HD + t];
        float v1 = xw[(long long)c1 * HD + t];
        float v2 = xw[(long long)c2 * HD + t];
        float v3 = xw[(long long)c3 * HD + t];
        acc += v0; acc += v1; acc += v2; acc += v3;
    }
    for (; j < s1; ++j) acc += xw[(long long)scol[j] * HD + t];
    acc = fmaxf(acc, 0.f);

    float up = acc * Wedge[t];
    float vp = acc * Wedge[HD + t];
#pragma unroll
    for (int off = 32; off > 0; off >>= 1) {
        up += __shfl_down(up, off);
        vp += __shfl_down(vp, off);
    }
    __shared__ float su[2], sv[2];
    int wid = t >> 6;
    if ((t & 63) == 0) { su[wid] = up; sv[wid] = vp; }
    __syncthreads();
    if (t == 0) { u[i] = su[0] + su[1]; v[i] = sv[0] + sv[1]; }

    // 8/16 of the dense adj zero-fill
    long long ft = (long long)i * 128 + t;
    float4 z = make_float4(0.f, 0.f, 0.f, 0.f);
#pragma unroll
    for (int jj = 0; jj < 8; ++jj)
        zq[Z_KE + ft + (long long)jj * 1048576] = z;
}

// K_F: edge logits; +1/16 fill; per-block min/max partials; last block reduces
// and publishes lo/hi to ctrl[8..9] (as floats).
__global__ __launch_bounds__(256) void kF_elog(const int* __restrict__ row,
                                               const int* __restrict__ col,
                                               const float* __restrict__ u,
                                               const float* __restrict__ v,
                                               const float* __restrict__ b_edge,
                                               float* __restrict__ elog,
                                               float* __restrict__ pmn,
                                               float* __restrict__ pmx,
                                               unsigned* __restrict__ ctrl,
                                               float4* __restrict__ zq) {
    int gid = blockIdx.x * 256 + threadIdx.x;
    float el = u[row[gid]] + v[col[gid]] + b_edge[0];
    elog[gid] = el;

    float4 z = make_float4(0.f, 0.f, 0.f, 0.f);
#pragma unroll
    for (int j = 0; j < 4; ++j)
        zq[Z_KF + gid + (long long)j * ED] = z;

    float mn = el, mx = el;
#pragma unroll
    for (int off = 32; off > 0; off >>= 1) {
        mn = fminf(mn, __shfl_xor(mn, off));
        mx = fmaxf(mx, __shfl_xor(mx, off));
    }
    __shared__ float smn[4], smx[4];
    __shared__ unsigned tkt;
    int w = threadIdx.x >> 6;
    if ((threadIdx.x & 63) == 0) { smn[w] = mn; smx[w] = mx; }
    __syncthreads();
    if (threadIdx.x == 0) {
        pmn[blockIdx.x] = fminf(fminf(smn[0], smn[1]), fminf(smn[2], smn[3]));
        pmx[blockIdx.x] = fmaxf(fmaxf(smx[0], smx[1]), fmaxf(smx[2], smx[3]));
        __threadfence();
        tkt = atomicAdd(&ctrl[4], 1u);
    }
    __syncthreads();
    if (tkt == gridDim.x - 1) {
        __threadfence();
        int t = threadIdx.x;
        float4 a = ((const float4*)pmn)[t];
        float4 b = ((const float4*)pmx)[t];
        float m2 = fminf(fminf(a.x, a.y), fminf(a.z, a.w));
        float x2 = fmaxf(fmaxf(b.x, b.y), fmaxf(b.z, b.w));
#pragma unroll
        for (int off = 32; off > 0; off >>= 1) {
            m2 = fminf(m2, __shfl_xor(m2, off));
            x2 = fmaxf(x2, __shfl_xor(x2, off));
        }
        __shared__ float rmn[4], rmx[4];
        if ((t & 63) == 0) { rmn[t >> 6] = m2; rmx[t >> 6] = x2; }
        __syncthreads();
        if (t == 0) {
            float* flh = (float*)&ctrl[8];
            flh[0] = fminf(fminf(rmn[0], rmn[1]), fminf(rmn[2], rmn[3]));
            flh[1] = fmaxf(fmaxf(rmx[0], rmx[1]), fmaxf(rmx[2], rmx[3]));
        }
    }
}

// K_G: per-edge hard bit + winner election (last-edge-wins via max(e+1)).
__global__ void kG_hard(const int* __restrict__ row, const int* __restrict__ col,
                        const float* __restrict__ elog, const float* __restrict__ noise,
                        const unsigned* __restrict__ ctrl,
                        unsigned char* __restrict__ hard, int* __restrict__ adjI) {
    int gid = blockIdx.x * 256 + threadIdx.x;
    const float* flh = (const float*)&ctrl[8];
    float lo = flh[0];
    float hi = flh[1];
    float kk = 0.3f / (hi - lo);                // ub=0.3, lb=0
    float pr = kk * (elog[gid] - lo);
    float lp = logf(pr + 1e-10f) - log1pf(1e-10f - pr);
    long long cell = (long long)row[gid] * NND + col[gid];
    float nz = noise[cell];
    float lg = logf(nz) - log1pf(-nz);
    int h = ((lp + lg) > 0.f) ? 1 : 0;          // round(sigmoid(z/T)) == (z>0)
    hard[gid] = (unsigned char)h;
    atomicMax(&adjI[cell], gid + 1);
}

// K_H: winner writes adj value; per-block counts; last block writes rate.
__global__ __launch_bounds__(256) void kH_write(const int* __restrict__ row,
                                                const int* __restrict__ col,
                                                const unsigned char* __restrict__ hard,
                                                int* __restrict__ adjI,
                                                int* __restrict__ pcu,
                                                int* __restrict__ pcz,
                                                unsigned* __restrict__ ctrl,
                                                float* __restrict__ rate) {
    int gid = blockIdx.x * 256 + threadIdx.x;
    long long cell = (long long)row[gid] * NND + col[gid];
    int w = adjI[cell];
    bool win = (w == gid + 1);
    bool nzv = win && (hard[gid] == 0);
    if (win) ((float*)adjI)[cell] = nzv ? 1.0f : 0.0f;
    unsigned long long mw = __ballot(win);
    unsigned long long mz = __ballot(nzv);
    __shared__ int scu[4], scz[4];
    __shared__ unsigned tkt;
    int wd = threadIdx.x >> 6;
    if ((threadIdx.x & 63) == 0) { scu[wd] = __popcll(mw); scz[wd] = __popcll(mz); }
    __syncthreads();
    if (threadIdx.x == 0) {
        pcu[blockIdx.x] = scu[0] + scu[1] + scu[2] + scu[3];
        pcz[blockIdx.x] = scz[0] + scz[1] + scz[2] + scz[3];
        __threadfence();
        tkt = atomicAdd(&ctrl[5], 1u);
    }
    __syncthreads();
    if (tkt == gridDim.x - 1) {
        __threadfence();
        int t = threadIdx.x;
        int4 a = ((const int4*)pcu)[t];
        int4 b = ((const int4*)pcz)[t];
        int cu = a.x + a.y + a.z + a.w;
        int cz = b.x + b.y + b.z + b.w;
#pragma unroll
        for (int off = 32; off > 0; off >>= 1) {
            cu += __shfl_down(cu, off);
            cz += __shfl_down(cz, off);
        }
        __shared__ int rcu[4], rcz[4];
        if ((t & 63) == 0) { rcu[t >> 6] = cu; rcz[t >> 6] = cz; }
        __syncthreads();
        if (t == 0)
            rate[0] = (float)(rcz[0] + rcz[1] + rcz[2] + rcz[3]) /
                      (float)(rcu[0] + rcu[1] + rcu[2] + rcu[3]);
    }
}

extern "C" void kernel_launch(void* const* d_in, const int* in_sizes, int n_in,
                              void* d_out, int out_size, void* d_ws, size_t ws_size,
                              hipStream_t stream) {
    const float* x     = (const float*)d_in[0];
    const int*   row   = (const int*)d_in[1];
    const int*   col   = (const int*)d_in[2];
    const float* Wenc  = (const float*)d_in[3];
    const float* Wedge = (const float*)d_in[4];
    const float* bedge = (const float*)d_in[5];
    const float* noise = (const float*)d_in[6];
    const float* masku = (const float*)d_in[7];
    float* out = (float*)d_out;

    // workspace layout (~6.7 MB, same footprint as the passing round-2 kernel)
    char* ws = (char*)d_ws;
    float* xw        = (float*)(ws);                    // 4 MB
    float* elog      = (float*)(ws + 4194304);          // 1 MB
    float* u         = (float*)(ws + 5242880);          // 32 KB
    float* v         = (float*)(ws + 5275648);          // 32 KB
    int*   row_start = (int*)  (ws + 5308416);          // 36 KB reserve
    int*   cursor    = (int*)  (ws + 5345280);          // 32 KB
    int*   scol      = (int*)  (ws + 5378048);          // 1 MB
    int*   counts    = (int*)  (ws + 6426624);          // 32 KB
    unsigned char* hard = (unsigned char*)(ws + 6459392); // 256 KB
    unsigned* ctrl   = (unsigned*)(ws + 6721536);       // 64 B
    // partials alias buffers that are dead by the time they're used:
    float* pmn = (float*)cursor;            // cursor dead after kD
    float* pmx = pmn + 1024;
    int*   pcu = counts;                    // counts dead after kC
    int*   pcz = pcu + 1024;

    float4* zq  = (float4*)(out + NF_);
    int*    adjI = (int*)(out + NF_);
    float*  rate = out + NF_ + NN_;

    k0_init<<<32, 256, 0, stream>>>(counts, ctrl);
    k1_mega<<<GEMMB + FILLB, 256, 0, stream>>>(x, Wenc, masku, row, out, xw, counts);
    kC_scan<<<1, 256, 0, stream>>>(counts, row_start, cursor);
    kD_scatter<<<1024, 256, 0, stream>>>(row, col, cursor, scol, zq);
    kE_spmm_uv<<<8192, 128, 0, stream>>>(xw, row_start, scol, Wedge, u, v, zq);
    kF_elog<<<1024, 256, 0, stream>>>(row, col, u, v, bedge, elog, pmn, pmx, ctrl, zq);
    kG_hard<<<1024, 256, 0, stream>>>(row, col, elog, noise, ctrl, hard, adjI);
    kH_write<<<1024, 256, 0, stream>>>(row, col, hard, adjI, pcu, pcz, ctrl, rate);
}